// Round 13
// baseline (166.616 us; speedup 1.0000x reference)
//
#include <hip/hip_runtime.h>
#include <hip/hip_fp16.h>
#include <float.h>

#define NN 100000
#define NE 1600000
#define NB 391        // buckets of 256 nodes (dst >> 8)
#define NBLK 512      // hist/partition blocks
#define CHUNK 3125    // NE / NBLK
#define TOT (NB * NBLK)              // 200192 hist entries
#define SCAN_B2 ((TOT + 255) / 256)  // 782
#define NODE1_B 782   // node1 blocks: 782*128 = 100096 rows (2 waves/row-group)
#define MAXB 12288    // LDS-staged bucket capacity (mean 4092, sigma 64 -> safe)

// ---------- edge loading (int32 vs int64, detected per-block) ----------

__device__ __forceinline__ void load_edge(const int* __restrict__ ei, int is64,
                                          int idx, int& s, int& d) {
    if (is64) {
        const long long* e64 = (const long long*)ei;
        s = (int)e64[idx]; d = (int)e64[NE + idx];
    } else {
        s = ei[idx]; d = ei[NE + idx];
    }
}

__device__ __forceinline__ int load_dst(const int* __restrict__ ei, int is64, int idx) {
    if (is64) return (int)((const long long*)ei)[NE + idx];
    return ei[NE + idx];
}

// first 64 words: odd words are all-zero iff int64 (values < 2^31).
__device__ __forceinline__ int detect64(const int* __restrict__ ei, int t, int* s_flag) {
    if (t < 64) {
        unsigned w = ((const unsigned*)ei)[t];
        unsigned long long m = __ballot((t & 1) && w != 0);
        if (t == 0) *s_flag = (m == 0) ? 1 : 0;
    }
    __syncthreads();
    return *s_flag;
}

// ---------- fused: histogram + layer-1 node transform ----------
// blocks [0, NBLK): per-(block,bucket) histogram of dst (LDS counters).
// blocks [NBLK, NBLK+NODE1_B): node1, col-split across wave pairs:
//   wave parity = column half (0: cols 0-15 / head0, 1: cols 16-31 / head1);
//   row = blk*128 + (wid>>1)*64 + lane. Each lane streams the full x row as
//   float4 and keeps 16 accumulators; W via wave-uniform scalar loads.
//   200K threads -> 2x the latency hiding of the lane-per-row version.

__global__ __launch_bounds__(256) void k_hist_node1(
    const int* __restrict__ ei, int* __restrict__ hist_g,
    const float* __restrict__ x, const float* __restrict__ W1,
    const float* __restrict__ att_d,
    uint4* __restrict__ h1r, float* __restrict__ ad1) {
    __shared__ int h[NB];
    __shared__ int s_flag;
    int t = threadIdx.x;
    if (blockIdx.x < NBLK) {
        // ---- histogram ----
        for (int i = t; i < NB; i += 256) h[i] = 0;
        int is64 = detect64(ei, t, &s_flag);   // barrier covers h zeroing
        int base = blockIdx.x * CHUNK;
        for (int k = t; k < CHUNK; k += 256) {
            int d = load_dst(ei, is64, base + k);
            atomicAdd(&h[d >> 8], 1);
        }
        __syncthreads();
        for (int i = t; i < NB; i += 256) hist_g[i * NBLK + blockIdx.x] = h[i];
    } else {
        // ---- node1 (col-split) ----
        int wid = t >> 6, lane = t & 63;
        int half = wid & 1;                    // 0: cols 0-15, 1: cols 16-31
        int row = (blockIdx.x - NBLK) * 128 + (wid >> 1) * 64 + lane;
        int r = row < NN ? row : NN - 1;
        const float4* xr = (const float4*)(x + (size_t)r * 128);
        const float* Wh = W1 + (half << 4);    // wave-uniform base
        float acc[16];
        #pragma unroll
        for (int j = 0; j < 16; ++j) acc[j] = 0.f;
        for (int k4 = 0; k4 < 32; ++k4) {      // 4 k-values per iter
            float4 a = xr[k4];
            const float* Wr = Wh + k4 * 128;   // wave-uniform -> scalar loads
            #pragma unroll
            for (int c = 0; c < 4; ++c) {
                float xs = c == 0 ? a.x : c == 1 ? a.y : c == 2 ? a.z : a.w;
                #pragma unroll
                for (int j = 0; j < 16; ++j)
                    acc[j] = fmaf(xs, Wr[c * 32 + j], acc[j]);
            }
        }
        // alpha_dst for this head (att vector wave-uniform -> scalar loads)
        float dsum = 0.f;
        const float* ah = att_d + (half << 4);
        #pragma unroll
        for (int j = 0; j < 16; ++j) dsum = fmaf(acc[j], ah[j], dsum);
        if (row < NN) {
            unsigned pk[8];
            #pragma unroll
            for (int q = 0; q < 8; ++q) {
                __half2 hv = __floats2half2_rn(acc[2 * q], acc[2 * q + 1]);
                pk[q] = *(unsigned*)&hv;
            }
            h1r[row * 4 + half * 2]     = make_uint4(pk[0], pk[1], pk[2], pk[3]);
            h1r[row * 4 + half * 2 + 1] = make_uint4(pk[4], pk[5], pk[6], pk[7]);
            ad1[row * 2 + half] = dsum;
        }
    }
}

// ---------- scan phase 1: per-block sums of 256-entry hist chunks ----------

__global__ __launch_bounds__(256) void k_scan1(const int* __restrict__ hist_g,
                                               int* __restrict__ bsum) {
    __shared__ int part[4];
    int t = threadIdx.x;
    int i = blockIdx.x * 256 + t;
    int v = (i < TOT) ? hist_g[i] : 0;
    #pragma unroll
    for (int off = 32; off; off >>= 1) v += __shfl_xor(v, off);
    if ((t & 63) == 0) part[t >> 6] = v;
    __syncthreads();
    if (t == 0) bsum[blockIdx.x] = part[0] + part[1] + part[2] + part[3];
}

// ---------- scan phase 2+3 fused ----------

__global__ __launch_bounds__(256) void k_scan3(const int* __restrict__ hist_g,
                                               const int* __restrict__ bsum,
                                               int* __restrict__ hist_s,
                                               int* __restrict__ bbase) {
    __shared__ int red[4];
    __shared__ int s[256];
    int t = threadIdx.x, b = blockIdx.x;
    int partial = 0;
    for (int i = t; i < b; i += 256) partial += bsum[i];   // L2-hot
    #pragma unroll
    for (int off = 32; off; off >>= 1) partial += __shfl_xor(partial, off);
    if ((t & 63) == 0) red[t >> 6] = partial;
    int i = b * 256 + t;
    int v = (i < TOT) ? hist_g[i] : 0;
    s[t] = v;
    __syncthreads();
    int boff = red[0] + red[1] + red[2] + red[3];
    for (int off = 1; off < 256; off <<= 1) {
        int u = (t >= off) ? s[t - off] : 0;
        __syncthreads();
        s[t] += u;
        __syncthreads();
    }
    if (i < TOT) {
        int e = boff + s[t] - v;
        hist_s[i] = e;
        if ((i & (NBLK - 1)) == 0) bbase[i / NBLK] = e;
    }
    if (b == 0 && t == 0) bbase[NB] = NE;
}

// ---------- partition: place packed (src<<8 | dst&255) ----------

__global__ __launch_bounds__(512) void k_part(const int* __restrict__ ei,
                                              const int* __restrict__ hist_s,
                                              unsigned* __restrict__ pairs) {
    __shared__ int cur[NB];
    __shared__ int s_flag;
    int t = threadIdx.x;
    for (int i = t; i < NB; i += 512) cur[i] = hist_s[i * NBLK + blockIdx.x];
    int is64 = detect64(ei, t, &s_flag);
    int base = blockIdx.x * CHUNK;
    for (int k = t; k < CHUNK; k += 512) {
        int s, d; load_edge(ei, is64, base + k, s, d);
        int p = atomicAdd(&cur[d >> 8], 1);
        pairs[p] = ((unsigned)s << 8) | (unsigned)(d & 255);
    }
}

// ---------- per-bucket local CSR build (LDS-staged; srcs aliases pairs) ----------

__global__ __launch_bounds__(256) void k_csr(const unsigned* __restrict__ pairs,
                                             const int* __restrict__ bbase,
                                             int* __restrict__ offs,
                                             int* __restrict__ srcs) {
    __shared__ unsigned plds[MAXB];
    __shared__ int cnt_l[256];
    __shared__ int scan_l[256];
    int b = blockIdx.x, t = threadIdx.x;
    int beg = bbase[b], end = bbase[b + 1];
    int m = end - beg;
    if (m > MAXB) m = MAXB;
    for (int k = t; k < m; k += 256) plds[k] = pairs[beg + k];
    cnt_l[t] = 0;
    __syncthreads();
    for (int k = t; k < m; k += 256) atomicAdd(&cnt_l[plds[k] & 255], 1);
    __syncthreads();
    int v = cnt_l[t];
    scan_l[t] = v;
    __syncthreads();
    for (int off = 1; off < 256; off <<= 1) {
        int u = (t >= off) ? scan_l[t - off] : 0;
        __syncthreads();
        scan_l[t] += u;
        __syncthreads();
    }
    int lexcl = scan_l[t] - v;
    int node = (b << 8) + t;
    if (node < NN) offs[node] = beg + lexcl;
    if (b == 0 && t == 0) offs[NN] = NE;
    cnt_l[t] = lexcl;
    __syncthreads();
    for (int k = t; k < m; k += 256) {
        unsigned e = plds[k];
        int p = atomicAdd(&cnt_l[e & 255], 1);
        srcs[beg + p] = (int)(e >> 8);
    }
}

// ---------- layer 1 aggregate + fused relu + layer-2 transform ----------
// One wave per dst node: 8 edge-groups x 8 lanes x 4 feats (uint2 = 8B of the
// 64B interleaved fp16 row) -> 8 edges per loop iteration. alpha_src computed
// IN-REGISTER from the gathered row (dot4 + 2 shfl). ad1 read once per node.

__global__ __launch_bounds__(256) void k_agg1(
    const int* __restrict__ offs, const int* __restrict__ srcs,
    const float2* __restrict__ ad1, const uint2* __restrict__ h1x,
    const float* __restrict__ att_s, const float* __restrict__ b1,
    const float* __restrict__ W2, const float* __restrict__ as2w,
    const float* __restrict__ ad2w, uint2* __restrict__ hx) {
    int n = (blockIdx.x * blockDim.x + threadIdx.x) >> 6;
    if (n >= NN) return;
    int lane = threadIdx.x & 63;
    int eg = lane >> 3;          // edge group 0..7
    int j4 = lane & 7;           // feature quad: feats {4*j4 .. 4*j4+3}
    float4 av = ((const float4*)att_s)[j4];     // att_src quad for my feats
    int beg = offs[n];
    int deg = offs[n + 1] - beg;           // +1 virtual self-loop
    int tot = deg + 1;
    float2 adp = ad1[n];
    float adh = (j4 < 4) ? adp.x : adp.y;
    float ac0 = 0.f, ac1 = 0.f, ac2 = 0.f, ac3 = 0.f, dsum = 0.f;
    int k = eg;
    int s0 = (k < tot) ? ((k < deg) ? srcs[beg + k] : n) : 0;
    uint2 v0 = h1x[s0 * 8 + j4];
    for (; k < tot; k += 8) {
        int kn = k + 8;
        int s1 = (kn < tot) ? ((kn < deg) ? srcs[beg + kn] : n) : 0;
        uint2 v1 = h1x[s1 * 8 + j4];
        float2 fa = __half22float2(*(__half2*)&v0.x);
        float2 fb = __half22float2(*(__half2*)&v0.y);
        // alpha_src for own head: dot4 then sum the 4-lane quad
        float tsum = fa.x * av.x + fa.y * av.y + fb.x * av.z + fb.y * av.w;
        tsum += __shfl_xor(tsum, 1);
        tsum += __shfl_xor(tsum, 2);
        float e = tsum + adh;
        e = fmaxf(e, 0.2f * e);            // leaky_relu
        float p = __expf(e);
        ac0 = fmaf(p, fa.x, ac0);
        ac1 = fmaf(p, fa.y, ac1);
        ac2 = fmaf(p, fb.x, ac2);
        ac3 = fmaf(p, fb.y, ac3);
        if ((j4 & 3) == 0) dsum += p;      // lane j4==0 (head0), j4==4 (head1)
        s0 = s1; v0 = v1;
    }
    // reduce across the 8 edge groups (lane bits 3,4,5)
    #pragma unroll
    for (int off = 8; off <= 32; off <<= 1) {
        ac0 += __shfl_xor(ac0, off);
        ac1 += __shfl_xor(ac1, off);
        ac2 += __shfl_xor(ac2, off);
        ac3 += __shfl_xor(ac3, off);
        dsum += __shfl_xor(dsum, off);
    }
    float denom = __shfl(dsum, j4 & 4);    // lane 0 -> head0, lane 4 -> head1
    float inv = 1.f / (denom + 1e-16f);
    // fused epilogue (all 8 edge groups duplicate, harmless)
    float4 bb = ((const float4*)b1)[j4];
    float r0 = fmaxf(ac0 * inv + bb.x, 0.f);
    float r1 = fmaxf(ac1 * inv + bb.y, 0.f);
    float r2 = fmaxf(ac2 * inv + bb.z, 0.f);
    float r3 = fmaxf(ac3 * inv + bb.w, 0.f);
    float4 wA = ((const float4*)W2)[2 * j4];      // rows 4j4,4j4+1 x cols {0,1}
    float4 wB = ((const float4*)W2)[2 * j4 + 1];  // rows 4j4+2,4j4+3
    float c0 = r0 * wA.x + r1 * wA.z + r2 * wB.x + r3 * wB.z;
    float c1 = r0 * wA.y + r1 * wA.w + r2 * wB.y + r3 * wB.w;
    #pragma unroll
    for (int off = 4; off; off >>= 1) {
        c0 += __shfl_xor(c0, off);
        c1 += __shfl_xor(c1, off);
    }
    if (lane == 0) {
        float a_s = c0 * as2w[0] + c1 * as2w[1];
        float a_d = c0 * ad2w[0] + c1 * ad2w[1];
        __half2 lo = __floats2half2_rn(c0, c1);
        __half2 hi = __floats2half2_rn(a_s, a_d);
        uint2 pk;
        pk.x = *(unsigned*)&lo;
        pk.y = *(unsigned*)&hi;
        hx[n] = pk;
    }
}

// ---------- layer 2 aggregate: 16 lanes per dst node, value-prefetched ----------

__global__ __launch_bounds__(256) void k_agg2(
    const int* __restrict__ offs, const int* __restrict__ srcs,
    const uint2* __restrict__ hx, const float* __restrict__ b2,
    float* __restrict__ out) {
    int n = (blockIdx.x * blockDim.x + threadIdx.x) >> 4;
    if (n >= NN) return;
    int lane = threadIdx.x & 15;
    int beg = offs[n];
    int deg = offs[n + 1] - beg;
    uint2 mynode = hx[n];
    __half2 myhi = *(__half2*)&mynode.y;
    float adv = __high2float(myhi);
    float dsum = 0.f, s0acc = 0.f, s1acc = 0.f;
    int k = lane;
    int s0 = (k <= deg) ? ((k < deg) ? srcs[beg + k] : n) : 0;
    uint2 r0 = hx[s0];
    for (; k <= deg; k += 16) {
        int kn = k + 16;
        int s1 = (kn <= deg) ? ((kn < deg) ? srcs[beg + kn] : n) : 0;
        uint2 r1 = hx[s1];
        __half2 lo = *(__half2*)&r0.x;   // {h2_0, h2_1}
        __half2 hi = *(__half2*)&r0.y;   // {as2, ad2}
        float e = __low2float(hi) + adv;
        e = fmaxf(e, 0.2f * e);
        float p = __expf(e);
        dsum += p;
        s0acc = fmaf(p, __low2float(lo), s0acc);
        s1acc = fmaf(p, __high2float(lo), s1acc);
        r0 = r1;
    }
    #pragma unroll
    for (int off = 8; off; off >>= 1) {
        dsum  += __shfl_xor(dsum, off, 16);
        s0acc += __shfl_xor(s0acc, off, 16);
        s1acc += __shfl_xor(s1acc, off, 16);
    }
    if (lane == 0) {
        float inv = 1.f / (dsum + 1e-16f);
        out[n * 2]     = s0acc * inv + b2[0];
        out[n * 2 + 1] = s1acc * inv + b2[1];
    }
}

// ---------- launch ----------

extern "C" void kernel_launch(void* const* d_in, const int* in_sizes, int n_in,
                              void* d_out, int out_size, void* d_ws, size_t ws_size,
                              hipStream_t stream) {
    const float* x    = (const float*)d_in[0];
    const int*   ei   = (const int*)d_in[1];
    const float* W1   = (const float*)d_in[2];
    const float* as1w = (const float*)d_in[3];
    const float* ad1w = (const float*)d_in[4];
    const float* b1   = (const float*)d_in[5];
    const float* W2   = (const float*)d_in[6];
    const float* as2w = (const float*)d_in[7];
    const float* ad2w = (const float*)d_in[8];
    const float* b2   = (const float*)d_in[9];
    float* out = (float*)d_out;

    float* ws = (float*)d_ws;
    uint4* h1r = (uint4*)ws; ws += 16 * NN;   // 32 fp16/row = 64 B, 6.4 MB
    float* ad1 = ws; ws += 2 * NN;
    uint2* hx  = (uint2*)ws; ws += 2 * NN;
    int* offs   = (int*)ws; ws += NN + 1;
    int* srcs   = (int*)ws; ws += NE;
    int* hist_g = (int*)ws; ws += TOT;
    int* hist_s = (int*)ws; ws += TOT;
    int* bsum   = (int*)ws; ws += SCAN_B2;
    int* bbase  = (int*)ws; ws += NB + 1;
    unsigned* pairs = (unsigned*)srcs;  // alias: k_csr stages reads in LDS first

    k_hist_node1<<<NBLK + NODE1_B, 256, 0, stream>>>(ei, hist_g, x, W1, ad1w, h1r, ad1);
    k_scan1<<<SCAN_B2, 256, 0, stream>>>(hist_g, bsum);
    k_scan3<<<SCAN_B2, 256, 0, stream>>>(hist_g, bsum, hist_s, bbase);
    k_part<<<NBLK, 512, 0, stream>>>(ei, hist_s, pairs);
    k_csr<<<NB, 256, 0, stream>>>(pairs, bbase, offs, srcs);
    k_agg1<<<25000, 256, 0, stream>>>(offs, srcs, (const float2*)ad1, (const uint2*)h1r,
                                      as1w, b1, W2, as2w, ad2w, hx);
    k_agg2<<<6250, 256, 0, stream>>>(offs, srcs, hx, b2, out);
}

// Round 14
// 107.658 us; speedup vs baseline: 1.5476x; 1.5476x over previous
//
#include <hip/hip_runtime.h>
#include <hip/hip_fp16.h>
#include <float.h>

#define NN 100000
#define NE 1600000
#define NB 391        // buckets of 256 nodes (dst >> 8)
#define NBLK 512      // hist/partition blocks
#define CHUNK 3125    // NE / NBLK
#define TOT (NB * NBLK)              // 200192 hist entries
#define SCAN_B2 ((TOT + 255) / 256)  // 782
#define NODE1_B 1563  // node1 blocks: 1563*64 = 100032 rows
#define MAXB 12288    // LDS-staged bucket capacity (mean 4092, sigma 64 -> safe)
#define XPAD 136      // LDS x-tile row stride in halves (272 B = 16B-aligned)

typedef _Float16 f16x8 __attribute__((ext_vector_type(8)));
typedef _Float16 f16x4 __attribute__((ext_vector_type(4)));
typedef float f32x4 __attribute__((ext_vector_type(4)));

// ---------- edge loading (int32 vs int64, detected per-block) ----------

__device__ __forceinline__ void load_edge(const int* __restrict__ ei, int is64,
                                          int idx, int& s, int& d) {
    if (is64) {
        const long long* e64 = (const long long*)ei;
        s = (int)e64[idx]; d = (int)e64[NE + idx];
    } else {
        s = ei[idx]; d = ei[NE + idx];
    }
}

__device__ __forceinline__ int load_dst(const int* __restrict__ ei, int is64, int idx) {
    if (is64) return (int)((const long long*)ei)[NE + idx];
    return ei[NE + idx];
}

// first 64 words: odd words are all-zero iff int64 (values < 2^31).
__device__ __forceinline__ int detect64(const int* __restrict__ ei, int t, int* s_flag) {
    if (t < 64) {
        unsigned w = ((const unsigned*)ei)[t];
        unsigned long long m = __ballot((t & 1) && w != 0);
        if (t == 0) *s_flag = (m == 0) ? 1 : 0;
    }
    __syncthreads();
    return *s_flag;
}

// B fragment for mfma_f32_16x16x32_f16: lane holds col = lane&15 (of the
// 16-col n-tile), k = (lane>>4)*8 + i within the 32-wide c-tile.
__device__ __forceinline__ f16x8 load_bfrag(const float* __restrict__ W1,
                                            int n, int c, int g, int col) {
    f16x8 b;
    #pragma unroll
    for (int i = 0; i < 8; ++i)
        b[i] = (_Float16)W1[(c * 32 + g * 8 + i) * 32 + n * 16 + col];
    return b;
}

// ---------- fused: histogram + layer-1 node transform (MFMA) ----------
// blocks [0, NBLK): per-(block,bucket) histogram of dst (LDS counters).
// blocks [NBLK, NBLK+NODE1_B): node1 as a real GEMM:
//   stage 64 x-rows coalesced -> LDS fp16 [64][XPAD]; W held in VGPRs as 8
//   B-fragments (loaded once); 8 MFMAs per 16-row wave-tile; epilogue
//   computes alpha_dst from C-frags (C/D: col=lane&15, row=(lane>>4)*4+reg).

__global__ __launch_bounds__(256) void k_hist_node1(
    const int* __restrict__ ei, int* __restrict__ hist_g,
    const float* __restrict__ x, const float* __restrict__ W1,
    const float* __restrict__ att_d,
    uint4* __restrict__ h1r, float* __restrict__ ad1) {
    __shared__ __align__(16) char arena[64 * XPAD * 2];   // 17408 B
    __shared__ int s_flag;
    int t = threadIdx.x;
    if (blockIdx.x < NBLK) {
        // ---- histogram ----
        int* h = (int*)arena;
        for (int i = t; i < NB; i += 256) h[i] = 0;
        int is64 = detect64(ei, t, &s_flag);   // barrier covers h zeroing
        int base = blockIdx.x * CHUNK;
        for (int k = t; k < CHUNK; k += 256) {
            int d = load_dst(ei, is64, base + k);
            atomicAdd(&h[d >> 8], 1);
        }
        __syncthreads();
        for (int i = t; i < NB; i += 256) hist_g[i * NBLK + blockIdx.x] = h[i];
    } else {
        // ---- node1 GEMM ----
        _Float16* xs = (_Float16*)arena;
        int row0 = (blockIdx.x - NBLK) * 64;
        // stage 64 rows x 128 f32 -> fp16 LDS, fully coalesced float4 reads
        const float4* xg = (const float4*)x;
        #pragma unroll
        for (int i = 0; i < 8; ++i) {
            int f = i * 256 + t;
            int row = f >> 5, c4 = f & 31;
            int gr = row0 + row; if (gr >= NN) gr = NN - 1;
            float4 v = xg[(size_t)gr * 32 + c4];
            f16x4 hv = {(_Float16)v.x, (_Float16)v.y, (_Float16)v.z, (_Float16)v.w};
            *(f16x4*)(xs + row * XPAD + c4 * 4) = hv;
        }
        int w = t >> 6, lane = t & 63;
        int g = lane >> 4, col = lane & 15;   // col: C/D col & B col & A row
        // W fragments in VGPRs, loaded once (reused for the whole block)
        const f16x8 b00 = load_bfrag(W1, 0, 0, g, col);
        const f16x8 b01 = load_bfrag(W1, 0, 1, g, col);
        const f16x8 b02 = load_bfrag(W1, 0, 2, g, col);
        const f16x8 b03 = load_bfrag(W1, 0, 3, g, col);
        const f16x8 b10 = load_bfrag(W1, 1, 0, g, col);
        const f16x8 b11 = load_bfrag(W1, 1, 1, g, col);
        const f16x8 b12 = load_bfrag(W1, 1, 2, g, col);
        const f16x8 b13 = load_bfrag(W1, 1, 3, g, col);
        float at0 = att_d[col];        // head0 att_d for my col
        float at1 = att_d[16 + col];   // head1
        __syncthreads();
        // A frags: row = lane&15 within this wave's 16-row tile
        const _Float16* xrow = xs + (w * 16 + col) * XPAD;
        f16x8 a0 = *(const f16x8*)(xrow + 0 * 32 + g * 8);
        f16x8 a1 = *(const f16x8*)(xrow + 1 * 32 + g * 8);
        f16x8 a2 = *(const f16x8*)(xrow + 2 * 32 + g * 8);
        f16x8 a3 = *(const f16x8*)(xrow + 3 * 32 + g * 8);
        f32x4 acc0 = {0.f, 0.f, 0.f, 0.f};
        f32x4 acc1 = {0.f, 0.f, 0.f, 0.f};
        acc0 = __builtin_amdgcn_mfma_f32_16x16x32_f16(a0, b00, acc0, 0, 0, 0);
        acc0 = __builtin_amdgcn_mfma_f32_16x16x32_f16(a1, b01, acc0, 0, 0, 0);
        acc0 = __builtin_amdgcn_mfma_f32_16x16x32_f16(a2, b02, acc0, 0, 0, 0);
        acc0 = __builtin_amdgcn_mfma_f32_16x16x32_f16(a3, b03, acc0, 0, 0, 0);
        acc1 = __builtin_amdgcn_mfma_f32_16x16x32_f16(a0, b10, acc1, 0, 0, 0);
        acc1 = __builtin_amdgcn_mfma_f32_16x16x32_f16(a1, b11, acc1, 0, 0, 0);
        acc1 = __builtin_amdgcn_mfma_f32_16x16x32_f16(a2, b12, acc1, 0, 0, 0);
        acc1 = __builtin_amdgcn_mfma_f32_16x16x32_f16(a3, b13, acc1, 0, 0, 0);
        // epilogue: store h1 (fp16, interleaved 64B rows) + alpha_dst
        _Float16* h1h = (_Float16*)h1r;
        int rbase = row0 + w * 16;
        #pragma unroll
        for (int reg = 0; reg < 4; ++reg) {
            float v0 = acc0[reg], v1 = acc1[reg];
            int grow = rbase + g * 4 + reg;
            bool ok = grow < NN;
            if (ok) {
                h1h[grow * 32 + col]      = (_Float16)v0;
                h1h[grow * 32 + 16 + col] = (_Float16)v1;
            }
            float p0 = v0 * at0, p1 = v1 * at1;
            #pragma unroll
            for (int off = 1; off <= 8; off <<= 1) {
                p0 += __shfl_xor(p0, off);
                p1 += __shfl_xor(p1, off);
            }
            if (ok && col == 0) {
                ad1[grow * 2]     = p0;
                ad1[grow * 2 + 1] = p1;
            }
        }
    }
}

// ---------- scan phase 1: per-block sums of 256-entry hist chunks ----------

__global__ __launch_bounds__(256) void k_scan1(const int* __restrict__ hist_g,
                                               int* __restrict__ bsum) {
    __shared__ int part[4];
    int t = threadIdx.x;
    int i = blockIdx.x * 256 + t;
    int v = (i < TOT) ? hist_g[i] : 0;
    #pragma unroll
    for (int off = 32; off; off >>= 1) v += __shfl_xor(v, off);
    if ((t & 63) == 0) part[t >> 6] = v;
    __syncthreads();
    if (t == 0) bsum[blockIdx.x] = part[0] + part[1] + part[2] + part[3];
}

// ---------- scan phase 2+3 fused ----------

__global__ __launch_bounds__(256) void k_scan3(const int* __restrict__ hist_g,
                                               const int* __restrict__ bsum,
                                               int* __restrict__ hist_s,
                                               int* __restrict__ bbase) {
    __shared__ int red[4];
    __shared__ int s[256];
    int t = threadIdx.x, b = blockIdx.x;
    int partial = 0;
    for (int i = t; i < b; i += 256) partial += bsum[i];   // L2-hot
    #pragma unroll
    for (int off = 32; off; off >>= 1) partial += __shfl_xor(partial, off);
    if ((t & 63) == 0) red[t >> 6] = partial;
    int i = b * 256 + t;
    int v = (i < TOT) ? hist_g[i] : 0;
    s[t] = v;
    __syncthreads();
    int boff = red[0] + red[1] + red[2] + red[3];
    for (int off = 1; off < 256; off <<= 1) {
        int u = (t >= off) ? s[t - off] : 0;
        __syncthreads();
        s[t] += u;
        __syncthreads();
    }
    if (i < TOT) {
        int e = boff + s[t] - v;
        hist_s[i] = e;
        if ((i & (NBLK - 1)) == 0) bbase[i / NBLK] = e;
    }
    if (b == 0 && t == 0) bbase[NB] = NE;
}

// ---------- partition: place packed (src<<8 | dst&255) ----------

__global__ __launch_bounds__(512) void k_part(const int* __restrict__ ei,
                                              const int* __restrict__ hist_s,
                                              unsigned* __restrict__ pairs) {
    __shared__ int cur[NB];
    __shared__ int s_flag;
    int t = threadIdx.x;
    for (int i = t; i < NB; i += 512) cur[i] = hist_s[i * NBLK + blockIdx.x];
    int is64 = detect64(ei, t, &s_flag);
    int base = blockIdx.x * CHUNK;
    for (int k = t; k < CHUNK; k += 512) {
        int s, d; load_edge(ei, is64, base + k, s, d);
        int p = atomicAdd(&cur[d >> 8], 1);
        pairs[p] = ((unsigned)s << 8) | (unsigned)(d & 255);
    }
}

// ---------- per-bucket local CSR build (LDS-staged; srcs aliases pairs) ----------

__global__ __launch_bounds__(256) void k_csr(const unsigned* __restrict__ pairs,
                                             const int* __restrict__ bbase,
                                             int* __restrict__ offs,
                                             int* __restrict__ srcs) {
    __shared__ unsigned plds[MAXB];
    __shared__ int cnt_l[256];
    __shared__ int scan_l[256];
    int b = blockIdx.x, t = threadIdx.x;
    int beg = bbase[b], end = bbase[b + 1];
    int m = end - beg;
    if (m > MAXB) m = MAXB;
    for (int k = t; k < m; k += 256) plds[k] = pairs[beg + k];
    cnt_l[t] = 0;
    __syncthreads();
    for (int k = t; k < m; k += 256) atomicAdd(&cnt_l[plds[k] & 255], 1);
    __syncthreads();
    int v = cnt_l[t];
    scan_l[t] = v;
    __syncthreads();
    for (int off = 1; off < 256; off <<= 1) {
        int u = (t >= off) ? scan_l[t - off] : 0;
        __syncthreads();
        scan_l[t] += u;
        __syncthreads();
    }
    int lexcl = scan_l[t] - v;
    int node = (b << 8) + t;
    if (node < NN) offs[node] = beg + lexcl;
    if (b == 0 && t == 0) offs[NN] = NE;
    cnt_l[t] = lexcl;
    __syncthreads();
    for (int k = t; k < m; k += 256) {
        unsigned e = plds[k];
        int p = atomicAdd(&cnt_l[e & 255], 1);
        srcs[beg + p] = (int)(e >> 8);
    }
}

// ---------- layer 1 aggregate + fused relu + layer-2 transform ----------
// One wave per dst node: 8 edge-groups x 8 lanes x 4 feats (uint2 = 8B of the
// 64B interleaved fp16 row) -> 8 edges per loop iteration. alpha_src computed
// IN-REGISTER from the gathered row (dot4 + 2 shfl). ad1 read once per node.

__global__ __launch_bounds__(256) void k_agg1(
    const int* __restrict__ offs, const int* __restrict__ srcs,
    const float2* __restrict__ ad1, const uint2* __restrict__ h1x,
    const float* __restrict__ att_s, const float* __restrict__ b1,
    const float* __restrict__ W2, const float* __restrict__ as2w,
    const float* __restrict__ ad2w, uint2* __restrict__ hx) {
    int n = (blockIdx.x * blockDim.x + threadIdx.x) >> 6;
    if (n >= NN) return;
    int lane = threadIdx.x & 63;
    int eg = lane >> 3;          // edge group 0..7
    int j4 = lane & 7;           // feature quad: feats {4*j4 .. 4*j4+3}
    float4 av = ((const float4*)att_s)[j4];     // att_src quad for my feats
    int beg = offs[n];
    int deg = offs[n + 1] - beg;           // +1 virtual self-loop
    int tot = deg + 1;
    float2 adp = ad1[n];
    float adh = (j4 < 4) ? adp.x : adp.y;
    float ac0 = 0.f, ac1 = 0.f, ac2 = 0.f, ac3 = 0.f, dsum = 0.f;
    int k = eg;
    int s0 = (k < tot) ? ((k < deg) ? srcs[beg + k] : n) : 0;
    uint2 v0 = h1x[s0 * 8 + j4];
    for (; k < tot; k += 8) {
        int kn = k + 8;
        int s1 = (kn < tot) ? ((kn < deg) ? srcs[beg + kn] : n) : 0;
        uint2 v1 = h1x[s1 * 8 + j4];
        float2 fa = __half22float2(*(__half2*)&v0.x);
        float2 fb = __half22float2(*(__half2*)&v0.y);
        // alpha_src for own head: dot4 then sum the 4-lane quad
        float tsum = fa.x * av.x + fa.y * av.y + fb.x * av.z + fb.y * av.w;
        tsum += __shfl_xor(tsum, 1);
        tsum += __shfl_xor(tsum, 2);
        float e = tsum + adh;
        e = fmaxf(e, 0.2f * e);            // leaky_relu
        float p = __expf(e);
        ac0 = fmaf(p, fa.x, ac0);
        ac1 = fmaf(p, fa.y, ac1);
        ac2 = fmaf(p, fb.x, ac2);
        ac3 = fmaf(p, fb.y, ac3);
        if ((j4 & 3) == 0) dsum += p;      // lane j4==0 (head0), j4==4 (head1)
        s0 = s1; v0 = v1;
    }
    // reduce across the 8 edge groups (lane bits 3,4,5)
    #pragma unroll
    for (int off = 8; off <= 32; off <<= 1) {
        ac0 += __shfl_xor(ac0, off);
        ac1 += __shfl_xor(ac1, off);
        ac2 += __shfl_xor(ac2, off);
        ac3 += __shfl_xor(ac3, off);
        dsum += __shfl_xor(dsum, off);
    }
    float denom = __shfl(dsum, j4 & 4);    // lane 0 -> head0, lane 4 -> head1
    float inv = 1.f / (denom + 1e-16f);
    // fused epilogue (all 8 edge groups duplicate, harmless)
    float4 bb = ((const float4*)b1)[j4];
    float r0 = fmaxf(ac0 * inv + bb.x, 0.f);
    float r1 = fmaxf(ac1 * inv + bb.y, 0.f);
    float r2 = fmaxf(ac2 * inv + bb.z, 0.f);
    float r3 = fmaxf(ac3 * inv + bb.w, 0.f);
    float4 wA = ((const float4*)W2)[2 * j4];      // rows 4j4,4j4+1 x cols {0,1}
    float4 wB = ((const float4*)W2)[2 * j4 + 1];  // rows 4j4+2,4j4+3
    float c0 = r0 * wA.x + r1 * wA.z + r2 * wB.x + r3 * wB.z;
    float c1 = r0 * wA.y + r1 * wA.w + r2 * wB.y + r3 * wB.w;
    #pragma unroll
    for (int off = 4; off; off >>= 1) {
        c0 += __shfl_xor(c0, off);
        c1 += __shfl_xor(c1, off);
    }
    if (lane == 0) {
        float a_s = c0 * as2w[0] + c1 * as2w[1];
        float a_d = c0 * ad2w[0] + c1 * ad2w[1];
        __half2 lo = __floats2half2_rn(c0, c1);
        __half2 hi = __floats2half2_rn(a_s, a_d);
        uint2 pk;
        pk.x = *(unsigned*)&lo;
        pk.y = *(unsigned*)&hi;
        hx[n] = pk;
    }
}

// ---------- layer 2 aggregate: 16 lanes per dst node, value-prefetched ----------

__global__ __launch_bounds__(256) void k_agg2(
    const int* __restrict__ offs, const int* __restrict__ srcs,
    const uint2* __restrict__ hx, const float* __restrict__ b2,
    float* __restrict__ out) {
    int n = (blockIdx.x * blockDim.x + threadIdx.x) >> 4;
    if (n >= NN) return;
    int lane = threadIdx.x & 15;
    int beg = offs[n];
    int deg = offs[n + 1] - beg;
    uint2 mynode = hx[n];
    __half2 myhi = *(__half2*)&mynode.y;
    float adv = __high2float(myhi);
    float dsum = 0.f, s0acc = 0.f, s1acc = 0.f;
    int k = lane;
    int s0 = (k <= deg) ? ((k < deg) ? srcs[beg + k] : n) : 0;
    uint2 r0 = hx[s0];
    for (; k <= deg; k += 16) {
        int kn = k + 16;
        int s1 = (kn <= deg) ? ((kn < deg) ? srcs[beg + kn] : n) : 0;
        uint2 r1 = hx[s1];
        __half2 lo = *(__half2*)&r0.x;   // {h2_0, h2_1}
        __half2 hi = *(__half2*)&r0.y;   // {as2, ad2}
        float e = __low2float(hi) + adv;
        e = fmaxf(e, 0.2f * e);
        float p = __expf(e);
        dsum += p;
        s0acc = fmaf(p, __low2float(lo), s0acc);
        s1acc = fmaf(p, __high2float(lo), s1acc);
        r0 = r1;
    }
    #pragma unroll
    for (int off = 8; off; off >>= 1) {
        dsum  += __shfl_xor(dsum, off, 16);
        s0acc += __shfl_xor(s0acc, off, 16);
        s1acc += __shfl_xor(s1acc, off, 16);
    }
    if (lane == 0) {
        float inv = 1.f / (dsum + 1e-16f);
        out[n * 2]     = s0acc * inv + b2[0];
        out[n * 2 + 1] = s1acc * inv + b2[1];
    }
}

// ---------- launch ----------

extern "C" void kernel_launch(void* const* d_in, const int* in_sizes, int n_in,
                              void* d_out, int out_size, void* d_ws, size_t ws_size,
                              hipStream_t stream) {
    const float* x    = (const float*)d_in[0];
    const int*   ei   = (const int*)d_in[1];
    const float* W1   = (const float*)d_in[2];
    const float* as1w = (const float*)d_in[3];
    const float* ad1w = (const float*)d_in[4];
    const float* b1   = (const float*)d_in[5];
    const float* W2   = (const float*)d_in[6];
    const float* as2w = (const float*)d_in[7];
    const float* ad2w = (const float*)d_in[8];
    const float* b2   = (const float*)d_in[9];
    float* out = (float*)d_out;

    float* ws = (float*)d_ws;
    uint4* h1r = (uint4*)ws; ws += 16 * NN;   // 32 fp16/row = 64 B, 6.4 MB
    float* ad1 = ws; ws += 2 * NN;
    uint2* hx  = (uint2*)ws; ws += 2 * NN;
    int* offs   = (int*)ws; ws += NN + 1;
    int* srcs   = (int*)ws; ws += NE;
    int* hist_g = (int*)ws; ws += TOT;
    int* hist_s = (int*)ws; ws += TOT;
    int* bsum   = (int*)ws; ws += SCAN_B2;
    int* bbase  = (int*)ws; ws += NB + 1;
    unsigned* pairs = (unsigned*)srcs;  // alias: k_csr stages reads in LDS first

    k_hist_node1<<<NBLK + NODE1_B, 256, 0, stream>>>(ei, hist_g, x, W1, ad1w, h1r, ad1);
    k_scan1<<<SCAN_B2, 256, 0, stream>>>(hist_g, bsum);
    k_scan3<<<SCAN_B2, 256, 0, stream>>>(hist_g, bsum, hist_s, bbase);
    k_part<<<NBLK, 512, 0, stream>>>(ei, hist_s, pairs);
    k_csr<<<NB, 256, 0, stream>>>(pairs, bbase, offs, srcs);
    k_agg1<<<25000, 256, 0, stream>>>(offs, srcs, (const float2*)ad1, (const uint2*)h1r,
                                      as1w, b1, W2, as2w, ad2w, hx);
    k_agg2<<<6250, 256, 0, stream>>>(offs, srcs, hx, b2, out);
}

// Round 15
// 93.661 us; speedup vs baseline: 1.7789x; 1.1494x over previous
//
#include <hip/hip_runtime.h>
#include <hip/hip_fp16.h>
#include <float.h>

#define NN 100000
#define NE 1600000
#define NB 391        // buckets of 256 nodes (dst >> 8)
#define NBLK 512      // hist/partition blocks
#define CHUNK 3125    // NE / NBLK
#define TOT (NB * NBLK)              // 200192 hist entries
#define SCAN_B2 ((TOT + 255) / 256)  // 782
#define NODE1_B 1563  // node1 blocks: 1563*64 = 100032 rows
#define MAXB 12288    // LDS-staged bucket capacity (mean 4092, sigma 64 -> safe)
#define XPAD 136      // LDS x-tile row stride in halves (272 B = 16B-aligned)

typedef _Float16 f16x8 __attribute__((ext_vector_type(8)));
typedef _Float16 f16x4 __attribute__((ext_vector_type(4)));
typedef float f32x4 __attribute__((ext_vector_type(4)));

// ---------- edge loading (int32 vs int64, detected per-block) ----------

__device__ __forceinline__ void load_edge(const int* __restrict__ ei, int is64,
                                          int idx, int& s, int& d) {
    if (is64) {
        const long long* e64 = (const long long*)ei;
        s = (int)e64[idx]; d = (int)e64[NE + idx];
    } else {
        s = ei[idx]; d = ei[NE + idx];
    }
}

__device__ __forceinline__ int load_dst(const int* __restrict__ ei, int is64, int idx) {
    if (is64) return (int)((const long long*)ei)[NE + idx];
    return ei[NE + idx];
}

// first 64 words: odd words are all-zero iff int64 (values < 2^31).
__device__ __forceinline__ int detect64(const int* __restrict__ ei, int t, int* s_flag) {
    if (t < 64) {
        unsigned w = ((const unsigned*)ei)[t];
        unsigned long long m = __ballot((t & 1) && w != 0);
        if (t == 0) *s_flag = (m == 0) ? 1 : 0;
    }
    __syncthreads();
    return *s_flag;
}

// B fragment for mfma_f32_16x16x32_f16: lane holds col = lane&15 (of the
// 16-col n-tile), k = (lane>>4)*8 + i within the 32-wide c-tile.
__device__ __forceinline__ f16x8 load_bfrag(const float* __restrict__ W1,
                                            int n, int c, int g, int col) {
    f16x8 b;
    #pragma unroll
    for (int i = 0; i < 8; ++i)
        b[i] = (_Float16)W1[(c * 32 + g * 8 + i) * 32 + n * 16 + col];
    return b;
}

// ---------- fused: histogram + layer-1 node transform (MFMA) ----------

__global__ __launch_bounds__(256) void k_hist_node1(
    const int* __restrict__ ei, int* __restrict__ hist_g,
    const float* __restrict__ x, const float* __restrict__ W1,
    const float* __restrict__ att_d,
    uint4* __restrict__ h1r, float* __restrict__ ad1) {
    __shared__ __align__(16) char arena[64 * XPAD * 2];   // 17408 B
    __shared__ int s_flag;
    int t = threadIdx.x;
    if (blockIdx.x < NBLK) {
        // ---- histogram ----
        int* h = (int*)arena;
        for (int i = t; i < NB; i += 256) h[i] = 0;
        int is64 = detect64(ei, t, &s_flag);   // barrier covers h zeroing
        int base = blockIdx.x * CHUNK;
        for (int k = t; k < CHUNK; k += 256) {
            int d = load_dst(ei, is64, base + k);
            atomicAdd(&h[d >> 8], 1);
        }
        __syncthreads();
        for (int i = t; i < NB; i += 256) hist_g[i * NBLK + blockIdx.x] = h[i];
    } else {
        // ---- node1 GEMM ----
        _Float16* xs = (_Float16*)arena;
        int row0 = (blockIdx.x - NBLK) * 64;
        const float4* xg = (const float4*)x;
        #pragma unroll
        for (int i = 0; i < 8; ++i) {
            int f = i * 256 + t;
            int row = f >> 5, c4 = f & 31;
            int gr = row0 + row; if (gr >= NN) gr = NN - 1;
            float4 v = xg[(size_t)gr * 32 + c4];
            f16x4 hv = {(_Float16)v.x, (_Float16)v.y, (_Float16)v.z, (_Float16)v.w};
            *(f16x4*)(xs + row * XPAD + c4 * 4) = hv;
        }
        int w = t >> 6, lane = t & 63;
        int g = lane >> 4, col = lane & 15;
        const f16x8 b00 = load_bfrag(W1, 0, 0, g, col);
        const f16x8 b01 = load_bfrag(W1, 0, 1, g, col);
        const f16x8 b02 = load_bfrag(W1, 0, 2, g, col);
        const f16x8 b03 = load_bfrag(W1, 0, 3, g, col);
        const f16x8 b10 = load_bfrag(W1, 1, 0, g, col);
        const f16x8 b11 = load_bfrag(W1, 1, 1, g, col);
        const f16x8 b12 = load_bfrag(W1, 1, 2, g, col);
        const f16x8 b13 = load_bfrag(W1, 1, 3, g, col);
        float at0 = att_d[col];
        float at1 = att_d[16 + col];
        __syncthreads();
        const _Float16* xrow = xs + (w * 16 + col) * XPAD;
        f16x8 a0 = *(const f16x8*)(xrow + 0 * 32 + g * 8);
        f16x8 a1 = *(const f16x8*)(xrow + 1 * 32 + g * 8);
        f16x8 a2 = *(const f16x8*)(xrow + 2 * 32 + g * 8);
        f16x8 a3 = *(const f16x8*)(xrow + 3 * 32 + g * 8);
        f32x4 acc0 = {0.f, 0.f, 0.f, 0.f};
        f32x4 acc1 = {0.f, 0.f, 0.f, 0.f};
        acc0 = __builtin_amdgcn_mfma_f32_16x16x32_f16(a0, b00, acc0, 0, 0, 0);
        acc0 = __builtin_amdgcn_mfma_f32_16x16x32_f16(a1, b01, acc0, 0, 0, 0);
        acc0 = __builtin_amdgcn_mfma_f32_16x16x32_f16(a2, b02, acc0, 0, 0, 0);
        acc0 = __builtin_amdgcn_mfma_f32_16x16x32_f16(a3, b03, acc0, 0, 0, 0);
        acc1 = __builtin_amdgcn_mfma_f32_16x16x32_f16(a0, b10, acc1, 0, 0, 0);
        acc1 = __builtin_amdgcn_mfma_f32_16x16x32_f16(a1, b11, acc1, 0, 0, 0);
        acc1 = __builtin_amdgcn_mfma_f32_16x16x32_f16(a2, b12, acc1, 0, 0, 0);
        acc1 = __builtin_amdgcn_mfma_f32_16x16x32_f16(a3, b13, acc1, 0, 0, 0);
        _Float16* h1h = (_Float16*)h1r;
        int rbase = row0 + w * 16;
        #pragma unroll
        for (int reg = 0; reg < 4; ++reg) {
            float v0 = acc0[reg], v1 = acc1[reg];
            int grow = rbase + g * 4 + reg;
            bool ok = grow < NN;
            if (ok) {
                h1h[grow * 32 + col]      = (_Float16)v0;
                h1h[grow * 32 + 16 + col] = (_Float16)v1;
            }
            float p0 = v0 * at0, p1 = v1 * at1;
            #pragma unroll
            for (int off = 1; off <= 8; off <<= 1) {
                p0 += __shfl_xor(p0, off);
                p1 += __shfl_xor(p1, off);
            }
            if (ok && col == 0) {
                ad1[grow * 2]     = p0;
                ad1[grow * 2 + 1] = p1;
            }
        }
    }
}

// ---------- scan phase 1: per-block sums of 256-entry hist chunks ----------

__global__ __launch_bounds__(256) void k_scan1(const int* __restrict__ hist_g,
                                               int* __restrict__ bsum) {
    __shared__ int part[4];
    int t = threadIdx.x;
    int i = blockIdx.x * 256 + t;
    int v = (i < TOT) ? hist_g[i] : 0;
    #pragma unroll
    for (int off = 32; off; off >>= 1) v += __shfl_xor(v, off);
    if ((t & 63) == 0) part[t >> 6] = v;
    __syncthreads();
    if (t == 0) bsum[blockIdx.x] = part[0] + part[1] + part[2] + part[3];
}

// ---------- scan phase 2+3 fused ----------

__global__ __launch_bounds__(256) void k_scan3(const int* __restrict__ hist_g,
                                               const int* __restrict__ bsum,
                                               int* __restrict__ hist_s,
                                               int* __restrict__ bbase) {
    __shared__ int red[4];
    __shared__ int s[256];
    int t = threadIdx.x, b = blockIdx.x;
    int partial = 0;
    for (int i = t; i < b; i += 256) partial += bsum[i];   // L2-hot
    #pragma unroll
    for (int off = 32; off; off >>= 1) partial += __shfl_xor(partial, off);
    if ((t & 63) == 0) red[t >> 6] = partial;
    int i = b * 256 + t;
    int v = (i < TOT) ? hist_g[i] : 0;
    s[t] = v;
    __syncthreads();
    int boff = red[0] + red[1] + red[2] + red[3];
    for (int off = 1; off < 256; off <<= 1) {
        int u = (t >= off) ? s[t - off] : 0;
        __syncthreads();
        s[t] += u;
        __syncthreads();
    }
    if (i < TOT) {
        int e = boff + s[t] - v;
        hist_s[i] = e;
        if ((i & (NBLK - 1)) == 0) bbase[i / NBLK] = e;
    }
    if (b == 0 && t == 0) bbase[NB] = NE;
}

// ---------- partition: place packed (src<<8 | dst&255) ----------

__global__ __launch_bounds__(512) void k_part(const int* __restrict__ ei,
                                              const int* __restrict__ hist_s,
                                              unsigned* __restrict__ pairs) {
    __shared__ int cur[NB];
    __shared__ int s_flag;
    int t = threadIdx.x;
    for (int i = t; i < NB; i += 512) cur[i] = hist_s[i * NBLK + blockIdx.x];
    int is64 = detect64(ei, t, &s_flag);
    int base = blockIdx.x * CHUNK;
    for (int k = t; k < CHUNK; k += 512) {
        int s, d; load_edge(ei, is64, base + k, s, d);
        int p = atomicAdd(&cur[d >> 8], 1);
        pairs[p] = ((unsigned)s << 8) | (unsigned)(d & 255);
    }
}

// ---------- per-bucket local CSR build (LDS-staged; srcs aliases pairs) ----------

__global__ __launch_bounds__(256) void k_csr(const unsigned* __restrict__ pairs,
                                             const int* __restrict__ bbase,
                                             int* __restrict__ offs,
                                             int* __restrict__ srcs) {
    __shared__ unsigned plds[MAXB];
    __shared__ int cnt_l[256];
    __shared__ int scan_l[256];
    int b = blockIdx.x, t = threadIdx.x;
    int beg = bbase[b], end = bbase[b + 1];
    int m = end - beg;
    if (m > MAXB) m = MAXB;
    for (int k = t; k < m; k += 256) plds[k] = pairs[beg + k];
    cnt_l[t] = 0;
    __syncthreads();
    for (int k = t; k < m; k += 256) atomicAdd(&cnt_l[plds[k] & 255], 1);
    __syncthreads();
    int v = cnt_l[t];
    scan_l[t] = v;
    __syncthreads();
    for (int off = 1; off < 256; off <<= 1) {
        int u = (t >= off) ? scan_l[t - off] : 0;
        __syncthreads();
        scan_l[t] += u;
        __syncthreads();
    }
    int lexcl = scan_l[t] - v;
    int node = (b << 8) + t;
    if (node < NN) offs[node] = beg + lexcl;
    if (b == 0 && t == 0) offs[NN] = NE;
    cnt_l[t] = lexcl;
    __syncthreads();
    for (int k = t; k < m; k += 256) {
        unsigned e = plds[k];
        int p = atomicAdd(&cnt_l[e & 255], 1);
        srcs[beg + p] = (int)(e >> 8);
    }
}

// ---------- layer 1 aggregate + fused relu + layer-2 transform ----------
// FOUR nodes per wave: 16 lanes/node = 2 edge-groups x 8 feat-quads. Same
// 8-edges-per-wave-iteration loop throughput as before, but all per-node
// prologue/epilogue (reductions, W2, pack) is amortized over 4 nodes.

__global__ __launch_bounds__(256) void k_agg1(
    const int* __restrict__ offs, const int* __restrict__ srcs,
    const float2* __restrict__ ad1, const uint2* __restrict__ h1x,
    const float* __restrict__ att_s, const float* __restrict__ b1,
    const float* __restrict__ W2, const float* __restrict__ as2w,
    const float* __restrict__ ad2w, uint2* __restrict__ hx) {
    int n = (blockIdx.x * blockDim.x + threadIdx.x) >> 4;   // 16 lanes/node
    if (n >= NN) return;
    int lane = threadIdx.x & 63;
    int r = lane & 15;
    int eg = r >> 3;             // edge group 0..1
    int j4 = r & 7;              // feature quad: feats {4*j4 .. 4*j4+3}
    float4 av = ((const float4*)att_s)[j4];     // att_src quad for my feats
    int beg = offs[n];
    int deg = offs[n + 1] - beg;           // +1 virtual self-loop
    int tot = deg + 1;
    float2 adp = ad1[n];
    float adh = (j4 < 4) ? adp.x : adp.y;
    float ac0 = 0.f, ac1 = 0.f, ac2 = 0.f, ac3 = 0.f, dsum = 0.f;
    int k = eg;
    int s0 = (k < tot) ? ((k < deg) ? srcs[beg + k] : n) : 0;
    uint2 v0 = h1x[s0 * 8 + j4];
    for (; k < tot; k += 2) {
        int kn = k + 2;
        int s1 = (kn < tot) ? ((kn < deg) ? srcs[beg + kn] : n) : 0;
        uint2 v1 = h1x[s1 * 8 + j4];
        float2 fa = __half22float2(*(__half2*)&v0.x);
        float2 fb = __half22float2(*(__half2*)&v0.y);
        // alpha_src for own head: dot4 then sum the 4-lane quad
        float tsum = fa.x * av.x + fa.y * av.y + fb.x * av.z + fb.y * av.w;
        tsum += __shfl_xor(tsum, 1);
        tsum += __shfl_xor(tsum, 2);
        float e = tsum + adh;
        e = fmaxf(e, 0.2f * e);            // leaky_relu
        float p = __expf(e);
        ac0 = fmaf(p, fa.x, ac0);
        ac1 = fmaf(p, fa.y, ac1);
        ac2 = fmaf(p, fb.x, ac2);
        ac3 = fmaf(p, fb.y, ac3);
        if ((j4 & 3) == 0) dsum += p;      // lane j4==0 (head0), j4==4 (head1)
        s0 = s1; v0 = v1;
    }
    // reduce across the 2 edge groups (lane bit 3)
    ac0 += __shfl_xor(ac0, 8);
    ac1 += __shfl_xor(ac1, 8);
    ac2 += __shfl_xor(ac2, 8);
    ac3 += __shfl_xor(ac3, 8);
    dsum += __shfl_xor(dsum, 8);
    // head denom lives at r==0 (head0) / r==4 (head1) of this node's 16 lanes
    float denom = __shfl(dsum, (lane & 0x30) | (j4 & 4));
    float inv = 1.f / (denom + 1e-16f);
    // fused epilogue (both edge-group halves duplicate, harmless)
    float4 bb = ((const float4*)b1)[j4];
    float r0 = fmaxf(ac0 * inv + bb.x, 0.f);
    float r1 = fmaxf(ac1 * inv + bb.y, 0.f);
    float r2 = fmaxf(ac2 * inv + bb.z, 0.f);
    float r3 = fmaxf(ac3 * inv + bb.w, 0.f);
    float4 wA = ((const float4*)W2)[2 * j4];      // rows 4j4,4j4+1 x cols {0,1}
    float4 wB = ((const float4*)W2)[2 * j4 + 1];  // rows 4j4+2,4j4+3
    float c0 = r0 * wA.x + r1 * wA.z + r2 * wB.x + r3 * wB.z;
    float c1 = r0 * wA.y + r1 * wA.w + r2 * wB.y + r3 * wB.w;
    #pragma unroll
    for (int off = 4; off; off >>= 1) {
        c0 += __shfl_xor(c0, off);
        c1 += __shfl_xor(c1, off);
    }
    if (r == 0) {
        float a_s = c0 * as2w[0] + c1 * as2w[1];
        float a_d = c0 * ad2w[0] + c1 * ad2w[1];
        __half2 lo = __floats2half2_rn(c0, c1);
        __half2 hi = __floats2half2_rn(a_s, a_d);
        uint2 pk;
        pk.x = *(unsigned*)&lo;
        pk.y = *(unsigned*)&hi;
        hx[n] = pk;
    }
}

// ---------- layer 2 aggregate: 16 lanes per dst node, value-prefetched ----------

__global__ __launch_bounds__(256) void k_agg2(
    const int* __restrict__ offs, const int* __restrict__ srcs,
    const uint2* __restrict__ hx, const float* __restrict__ b2,
    float* __restrict__ out) {
    int n = (blockIdx.x * blockDim.x + threadIdx.x) >> 4;
    if (n >= NN) return;
    int lane = threadIdx.x & 15;
    int beg = offs[n];
    int deg = offs[n + 1] - beg;
    uint2 mynode = hx[n];
    __half2 myhi = *(__half2*)&mynode.y;
    float adv = __high2float(myhi);
    float dsum = 0.f, s0acc = 0.f, s1acc = 0.f;
    int k = lane;
    int s0 = (k <= deg) ? ((k < deg) ? srcs[beg + k] : n) : 0;
    uint2 r0 = hx[s0];
    for (; k <= deg; k += 16) {
        int kn = k + 16;
        int s1 = (kn <= deg) ? ((kn < deg) ? srcs[beg + kn] : n) : 0;
        uint2 r1 = hx[s1];
        __half2 lo = *(__half2*)&r0.x;   // {h2_0, h2_1}
        __half2 hi = *(__half2*)&r0.y;   // {as2, ad2}
        float e = __low2float(hi) + adv;
        e = fmaxf(e, 0.2f * e);
        float p = __expf(e);
        dsum += p;
        s0acc = fmaf(p, __low2float(lo), s0acc);
        s1acc = fmaf(p, __high2float(lo), s1acc);
        r0 = r1;
    }
    #pragma unroll
    for (int off = 8; off; off >>= 1) {
        dsum  += __shfl_xor(dsum, off, 16);
        s0acc += __shfl_xor(s0acc, off, 16);
        s1acc += __shfl_xor(s1acc, off, 16);
    }
    if (lane == 0) {
        float inv = 1.f / (dsum + 1e-16f);
        out[n * 2]     = s0acc * inv + b2[0];
        out[n * 2 + 1] = s1acc * inv + b2[1];
    }
}

// ---------- launch ----------

extern "C" void kernel_launch(void* const* d_in, const int* in_sizes, int n_in,
                              void* d_out, int out_size, void* d_ws, size_t ws_size,
                              hipStream_t stream) {
    const float* x    = (const float*)d_in[0];
    const int*   ei   = (const int*)d_in[1];
    const float* W1   = (const float*)d_in[2];
    const float* as1w = (const float*)d_in[3];
    const float* ad1w = (const float*)d_in[4];
    const float* b1   = (const float*)d_in[5];
    const float* W2   = (const float*)d_in[6];
    const float* as2w = (const float*)d_in[7];
    const float* ad2w = (const float*)d_in[8];
    const float* b2   = (const float*)d_in[9];
    float* out = (float*)d_out;

    float* ws = (float*)d_ws;
    uint4* h1r = (uint4*)ws; ws += 16 * NN;   // 32 fp16/row = 64 B, 6.4 MB
    float* ad1 = ws; ws += 2 * NN;
    uint2* hx  = (uint2*)ws; ws += 2 * NN;
    int* offs   = (int*)ws; ws += NN + 1;
    int* srcs   = (int*)ws; ws += NE;
    int* hist_g = (int*)ws; ws += TOT;
    int* hist_s = (int*)ws; ws += TOT;
    int* bsum   = (int*)ws; ws += SCAN_B2;
    int* bbase  = (int*)ws; ws += NB + 1;
    unsigned* pairs = (unsigned*)srcs;  // alias: k_csr stages reads in LDS first

    k_hist_node1<<<NBLK + NODE1_B, 256, 0, stream>>>(ei, hist_g, x, W1, ad1w, h1r, ad1);
    k_scan1<<<SCAN_B2, 256, 0, stream>>>(hist_g, bsum);
    k_scan3<<<SCAN_B2, 256, 0, stream>>>(hist_g, bsum, hist_s, bbase);
    k_part<<<NBLK, 512, 0, stream>>>(ei, hist_s, pairs);
    k_csr<<<NB, 256, 0, stream>>>(pairs, bbase, offs, srcs);
    k_agg1<<<6250, 256, 0, stream>>>(offs, srcs, (const float2*)ad1, (const uint2*)h1r,
                                     as1w, b1, W2, as2w, ad2w, hx);
    k_agg2<<<6250, 256, 0, stream>>>(offs, srcs, hx, b2, out);
}